// Round 6
// baseline (202.738 us; speedup 1.0000x reference)
//
#include <hip/hip_runtime.h>
#include <math.h>

#define D_MODEL 1024
#define NUM_EXPERTS 8
#define TOP_K 2
#define LPG 16                        // lanes per group
#define GTOK 2                        // tokens per group (W ds_read amortization)
#define GROUPS 4                      // 64 / LPG
#define TOKENS_PER_WAVE (GROUPS * GTOK)                       // 8
#define WAVES_PER_BLOCK 4
#define TOKENS_PER_BLOCK (TOKENS_PER_WAVE * WAVES_PER_BLOCK)  // 32

typedef float f4 __attribute__((ext_vector_type(4)));

// R6 = R4 with ONE variable changed: each W ds_read_b128 now feeds 2 tokens
// (4 groups broadcast x 2 tokens) -> LDS wave-insts/token 32 -> 16. Grid,
// blocks/CU (4), waves/CU (16) and register weight (~85 VGPR: acc 16 +
// xv 16) match R4. R5's confound (64-reg buf + grid 512) removed.
__global__ __launch_bounds__(256) void gating_kernel(
    const float* __restrict__ x, const float* __restrict__ W,
    const float* __restrict__ b, float* __restrict__ out_w,
    float* __restrict__ out_idx, int n_tokens)
{
    __shared__ float Wlds[NUM_EXPERTS * D_MODEL];  // 32 KB -> 5 blocks/CU cap

    {   // stage W: 2048 f4 across 256 threads -> 8 each
        const f4* Wg = (const f4*)W;
        f4* Ws = (f4*)Wlds;
        const int tid = threadIdx.x;
#pragma unroll
        for (int i = 0; i < (NUM_EXPERTS * D_MODEL / 4) / 256; ++i)
            Ws[tid + i * 256] = Wg[tid + i * 256];
    }
    __syncthreads();

    const int wave = threadIdx.x >> 6;
    const int lane = threadIdx.x & 63;
    const int g = lane >> 4;          // group 0..3
    const int l = lane & 15;          // lane-in-group
    const int tok0 = blockIdx.x * TOKENS_PER_BLOCK + wave * TOKENS_PER_WAVE + g * GTOK;
    if (tok0 >= n_tokens) return;

    // token row = 256 f4; lane l covers f4 idx l + kk*16, kk = 0..15
    const f4* xb = (const f4*)x + (size_t)tok0 * (D_MODEL / 4) + l;
    const f4* Wf = (const f4*)Wlds + l;

    float acc[GTOK][NUM_EXPERTS];
#pragma unroll
    for (int t = 0; t < GTOK; ++t)
#pragma unroll
        for (int e = 0; e < NUM_EXPERTS; ++e) acc[t][e] = 0.f;

    // light 1-ahead pipeline on the 2 token rows (4 f4 = 16 VGPR buffer)
    f4 xv[2][GTOK];
#pragma unroll
    for (int t = 0; t < GTOK; ++t)
        xv[0][t] = __builtin_nontemporal_load(xb + t * 256);

#pragma unroll
    for (int kk = 0; kk < 16; ++kk) {
        const int cur = kk & 1, nxt = cur ^ 1;
        if (kk < 15) {
#pragma unroll
            for (int t = 0; t < GTOK; ++t)
                xv[nxt][t] = __builtin_nontemporal_load(xb + t * 256 + (kk + 1) * 16);
        }
#pragma unroll
        for (int e = 0; e < NUM_EXPERTS; ++e) {
            const f4 wv = Wf[e * 256 + kk * 16];   // 4-group broadcast, conflict-free
#pragma unroll
            for (int t = 0; t < GTOK; ++t) {
                const f4 xt = xv[cur][t];
                acc[t][e] += xt.x * wv.x + xt.y * wv.y + xt.z * wv.z + xt.w * wv.w;
            }
        }
    }

    // Reduce across 16 lanes of the group (4 butterfly steps), add bias.
#pragma unroll
    for (int t = 0; t < GTOK; ++t)
#pragma unroll
        for (int e = 0; e < NUM_EXPERTS; ++e) {
            float v = acc[t][e];
            v += __shfl_xor(v, 1, 64);
            v += __shfl_xor(v, 2, 64);
            v += __shfl_xor(v, 4, 64);
            v += __shfl_xor(v, 8, 64);
            acc[t][e] = v + b[e];
        }

    // Lane l: token t = l>>3, role r = l&7 (8 lanes per token, 3 active).
    const int t = l >> 3;
    const int r = l & 7;
    const int token = tok0 + t;

    float v0 = -INFINITY, v1 = -INFINITY;
    int i0 = 0, i1 = 0;
#pragma unroll
    for (int e = 0; e < NUM_EXPERTS; ++e) {
        float v = acc[t][e];
        // strict > keeps lowest index on ties, matching jax.lax.top_k
        if (v > v0) { v1 = v0; i1 = i0; v0 = v; i0 = e; }
        else if (v > v1) { v1 = v; i1 = e; }
    }
    const float e1 = expf(v1 - v0);
    const float w0 = 1.f / (1.f + e1);
    const float w1 = e1 * w0;

    if (r < 2) {
        const int base = r * 4;
        f4 v4;
        v4.x = (base + 0 == i0) ? w0 : ((base + 0 == i1) ? w1 : 0.f);
        v4.y = (base + 1 == i0) ? w0 : ((base + 1 == i1) ? w1 : 0.f);
        v4.z = (base + 2 == i0) ? w0 : ((base + 2 == i1) ? w1 : 0.f);
        v4.w = (base + 3 == i0) ? w0 : ((base + 3 == i1) ? w1 : 0.f);
        ((f4*)(out_w + (size_t)token * NUM_EXPERTS))[r] = v4;
    } else if (r == 2) {
        *(float2*)(out_idx + (size_t)token * TOP_K) =
            make_float2((float)i0, (float)i1);
    }
}

extern "C" void kernel_launch(void* const* d_in, const int* in_sizes, int n_in,
                              void* d_out, int out_size, void* d_ws, size_t ws_size,
                              hipStream_t stream) {
    const float* x = (const float*)d_in[0];
    const float* W = (const float*)d_in[1];
    const float* b = (const float*)d_in[2];
    float* out = (float*)d_out;

    const int n_tokens = in_sizes[0] / D_MODEL;              // 32768
    float* out_w   = out;                                    // [n_tokens, 8]
    float* out_idx = out + (size_t)n_tokens * NUM_EXPERTS;   // [n_tokens, 2] as float

    const int grid = (n_tokens + TOKENS_PER_BLOCK - 1) / TOKENS_PER_BLOCK;  // 1024
    gating_kernel<<<grid, 256, 0, stream>>>(x, W, b, out_w, out_idx, n_tokens);
}